// Round 13
// baseline (1914.350 us; speedup 1.0000x reference)
//
#include <hip/hip_runtime.h>
#include <cstddef>
#include <cstdint>

#define B_ 512
#define T_ 2048
#define I_ 16
#define H_ 40

typedef __fp16 half_t;
typedef half_t h2 __attribute__((ext_vector_type(2)));
typedef float f4 __attribute__((ext_vector_type(4)));

// tanh(x) = 1 - 2/(exp(2x)+1); exp(2x) = exp2(x * 2*log2(e)).
__device__ __forceinline__ float fast_tanh(float x) {
  float e = __builtin_amdgcn_exp2f(x * 2.8853900817779268f);
  return 1.0f - 2.0f * __builtin_amdgcn_rcpf(e + 1.0f);
}
// v_dot2_f32_f16: 2 fp16 MACs with f32 accumulate.
__device__ __forceinline__ float dot2(h2 a, h2 b, float c) {
  return __builtin_amdgcn_fdot2(a, b, c, false);
}
// Use-site fp16 pack (volatile anchor: cannot be hoisted next to the load).
__device__ __forceinline__ h2 cvtpk_v(float lo, float hi) {
  h2 r;
  asm volatile("v_cvt_pkrtz_f16_f32 %0, %1, %2" : "=v"(r) : "v"(lo), "v"(hi));
  return r;
}
#define PIN(v) asm volatile("" : "+v"(v))

// ASYNC x loads via volatile asm (r9-proven decoupling), literal offsets.
#define GLOADQ_LO(R0, R1, R2, R3, P)                                \
  asm volatile("global_load_dwordx4 %0, %4, off\n\t"                \
               "global_load_dwordx4 %1, %4, off offset:16\n\t"      \
               "global_load_dwordx4 %2, %4, off offset:32\n\t"      \
               "global_load_dwordx4 %3, %4, off offset:48"          \
               : "=&v"(R0), "=&v"(R1), "=&v"(R2), "=&v"(R3)         \
               : "v"(P))
#define GLOADQ_HI(R0, R1, R2, R3, P)                                \
  asm volatile("global_load_dwordx4 %0, %4, off offset:64\n\t"      \
               "global_load_dwordx4 %1, %4, off offset:80\n\t"      \
               "global_load_dwordx4 %2, %4, off offset:96\n\t"      \
               "global_load_dwordx4 %3, %4, off offset:112"         \
               : "=&v"(R0), "=&v"(R1), "=&v"(R2), "=&v"(R3)         \
               : "v"(P))
// Counted wait, no sched fence (r11-proven: volatile ordering suffices).
#define WAITX(N) asm volatile("s_waitcnt vmcnt(" #N ")")

// Pack one f32 weight row into resident half2 VGPRs (shared by both streams).
#define LOADW(DST, SRC, STR, N2)                                    \
  _Pragma("unroll") for (int k = 0; k < (N2); ++k) {                \
    DST[k][0] = (half_t)SRC[jr * (STR) + 2 * k];                    \
    DST[k][1] = (half_t)SRC[jr * (STR) + 2 * k + 1];                \
    PIN(DST[k]);                                                    \
  }

// Register-only h broadcast (r10-proven): dpp XOR-1 -> cvt_pkrtz pair in even
// lane -> 20 readlanes into uniform pairs.
#define BCAST(NH, PAIRS) do {                                       \
  int nb_ = __builtin_amdgcn_update_dpp(                            \
      0, __builtin_bit_cast(int, (NH)), 0xB1, 0xf, 0xf, false);     \
  h2 pk_ = __builtin_amdgcn_cvt_pkrtz((NH),                         \
      __builtin_bit_cast(float, nb_));                              \
  int pkb_ = __builtin_bit_cast(int, pk_);                          \
  _Pragma("unroll") for (int p = 0; p < H_ / 2; ++p)                \
    PAIRS[p] = __builtin_bit_cast(h2,                               \
        __builtin_amdgcn_readlane(pkb_, 2 * p));                    \
} while (0)

// 40-wide dot: 20 dot2 of uniform pairs against resident weights.
#define HDS(PAIRS, W, A0, A1, A2, A3)                               \
  _Pragma("unroll") for (int p = 0; p < 5; ++p) {                   \
    A0 = dot2(PAIRS[4 * p + 0], (W)[4 * p + 0], A0);                \
    A1 = dot2(PAIRS[4 * p + 1], (W)[4 * p + 1], A1);                \
    A2 = dot2(PAIRS[4 * p + 2], (W)[4 * p + 2], A2);                \
    A3 = dot2(PAIRS[4 * p + 3], (W)[4 * p + 3], A3);                \
  }

// One RNN time step for one stream (r10/r11 structure, zero LDS).
#define STEP(XH, HP0, HP1, HP2, NH2V) do {                          \
  float a0 = bias0, a1 = 0.f, a2 = 0.f, a3 = 0.f;                   \
  a0 = dot2(XH[0], w0i[0], a0); a1 = dot2(XH[1], w0i[1], a1);       \
  a2 = dot2(XH[2], w0i[2], a2); a3 = dot2(XH[3], w0i[3], a3);       \
  a0 = dot2(XH[4], w0i[4], a0); a1 = dot2(XH[5], w0i[5], a1);       \
  a2 = dot2(XH[6], w0i[6], a2); a3 = dot2(XH[7], w0i[7], a3);       \
  HDS(HP0, w0h, a0, a1, a2, a3);                                    \
  const float nh0 = fast_tanh((a0 + a1) + (a2 + a3));               \
  BCAST(nh0, HP0);                                                  \
  float b0v = bias1, b1v = 0.f, b2v = 0.f, b3v = 0.f;               \
  HDS(HP0, w1i, b0v, b1v, b2v, b3v);  /* NEW h0 */                  \
  HDS(HP1, w1h, b0v, b1v, b2v, b3v);  /* old h1 */                  \
  const float nh1 = fast_tanh((b0v + b1v) + (b2v + b3v));           \
  BCAST(nh1, HP1);                                                  \
  float c0v = bias2, c1v = 0.f, c2v = 0.f, c3v = 0.f;               \
  HDS(HP1, w2i, c0v, c1v, c2v, c3v);  /* NEW h1 */                  \
  HDS(HP2, w2h, c0v, c1v, c2v, c3v);  /* old h2 */                  \
  NH2V = fast_tanh((c0v + c1v) + (c2v + c3v));                      \
  BCAST(NH2V, HP2);                                                 \
} while (0)

#define PACKX(XH, R0, R1, R2, R3)                                   \
  do {                                                              \
    XH[0] = cvtpk_v(R0[0], R0[1]); XH[1] = cvtpk_v(R0[2], R0[3]);   \
    XH[2] = cvtpk_v(R1[0], R1[1]); XH[3] = cvtpk_v(R1[2], R1[3]);   \
    XH[4] = cvtpk_v(R2[0], R2[1]); XH[5] = cvtpk_v(R2[2], R2[3]);   \
    XH[6] = cvtpk_v(R3[0], R3[1]); XH[7] = cvtpk_v(R3[2], R3[3]);   \
  } while (0)

__global__ __launch_bounds__(64)
__attribute__((amdgpu_waves_per_eu(1, 1)))  // full 512-reg budget
void rnn3_fused(const float* __restrict__ x,
                const float* __restrict__ wih0, const float* __restrict__ whh0,
                const float* __restrict__ bih0, const float* __restrict__ bhh0,
                const float* __restrict__ wih1, const float* __restrict__ whh1,
                const float* __restrict__ b_ih1, const float* __restrict__ bhh1,
                const float* __restrict__ wih2, const float* __restrict__ whh2,
                const float* __restrict__ bih2, const float* __restrict__ bhh2,
                const float* __restrict__ fcw, const float* __restrict__ fcb,
                float* __restrict__ out) {
  const int b0 = 2 * blockIdx.x;            // streams: batches b0, b0+1
  const int j = threadIdx.x;
  const int jr = (j < H_) ? j : (H_ - 1);

  // ---- shared weights packed fp16: 108 resident VGPRs ----
  h2 w0i[I_ / 2], w0h[H_ / 2], w1i[H_ / 2], w1h[H_ / 2], w2i[H_ / 2], w2h[H_ / 2];
  LOADW(w0i, wih0, I_, I_ / 2)
  LOADW(w0h, whh0, H_, H_ / 2)
  LOADW(w1i, wih1, H_, H_ / 2)
  LOADW(w1h, whh1, H_, H_ / 2)
  LOADW(w2i, wih2, H_, H_ / 2)
  LOADW(w2h, whh2, H_, H_ / 2)

  float bias0 = bih0[jr] + bhh0[jr];  PIN(bias0);
  float bias1 = b_ih1[jr] + bhh1[jr]; PIN(bias1);
  float bias2 = bih2[jr] + bhh2[jr];  PIN(bias2);

  // per-stream h state (uniform fp16 pairs; h(0)=0)
  h2 hpA0[20], hpA1[20], hpA2[20], hpB0[20], hpB1[20], hpB2[20];
#pragma unroll
  for (int p = 0; p < 20; ++p) {
    hpA0[p] = h2{(half_t)0.f, (half_t)0.f}; hpA1[p] = hpA0[p]; hpA2[p] = hpA0[p];
    hpB0[p] = hpA0[p]; hpB1[p] = hpA0[p]; hpB2[p] = hpA0[p];
  }

  const float* __restrict__ xb0 = x + (size_t)b0 * (T_ * I_);
  const float* __restrict__ xb1 = xb0 + (size_t)(T_ * I_);

  // 4 async groups in flight (16 loads): s0@t, s1@t, s0@t+1, s1@t+1.
  f4 a00, a01, a02, a03, a10, a11, a12, a13;   // stream0 t / t+1
  f4 c00, c01, c02, c03, c10, c11, c12, c13;   // stream1 t / t+1
  GLOADQ_LO(a00, a01, a02, a03, xb0);
  GLOADQ_LO(c00, c01, c02, c03, xb1);
  GLOADQ_HI(a10, a11, a12, a13, xb0);
  GLOADQ_HI(c10, c11, c12, c13, xb1);

  float nh2A = 0.f, nh2B = 0.f;
  h2 xh[8];

  for (int t = 0; t < T_; t += 2) {
    // next pair base (clamped to the last even pair; tail loads never consumed)
    const float* pf0 = xb0 + (size_t)((t + 2 < T_) ? (t + 2) : (T_ - 2)) * I_;
    const float* pf1 = xb1 + (size_t)((t + 2 < T_) ? (t + 2) : (T_ - 2)) * I_;

    WAITX(12);                                    // s0 @ t ready
    PACKX(xh, a00, a01, a02, a03);
    STEP(xh, hpA0, hpA1, hpA2, nh2A);
    GLOADQ_LO(a00, a01, a02, a03, pf0);           // s0 @ t+2

    WAITX(12);                                    // s1 @ t ready
    PACKX(xh, c00, c01, c02, c03);
    STEP(xh, hpB0, hpB1, hpB2, nh2B);
    GLOADQ_LO(c00, c01, c02, c03, pf1);           // s1 @ t+2

    WAITX(12);                                    // s0 @ t+1 ready
    PACKX(xh, a10, a11, a12, a13);
    STEP(xh, hpA0, hpA1, hpA2, nh2A);
    GLOADQ_HI(a10, a11, a12, a13, pf0);           // s0 @ t+3

    WAITX(12);                                    // s1 @ t+1 ready
    PACKX(xh, c10, c11, c12, c13);
    STEP(xh, hpB0, hpB1, hpB2, nh2B);
    GLOADQ_HI(c10, c11, c12, c13, pf1);           // s1 @ t+3
  }

  // Drain async loads before their destination registers are reused.
  asm volatile("s_waitcnt vmcnt(0)");
  PIN(a00); PIN(a01); PIN(a02); PIN(a03);
  PIN(a10); PIN(a11); PIN(a12); PIN(a13);
  PIN(c00); PIN(c01); PIN(c02); PIN(c03);
  PIN(c10); PIN(c11); PIN(c12); PIN(c13);

  // ---- FC head for both streams ----
  const float fw = (j < H_) ? fcw[j] : 0.f;
  float va = nh2A * fw;
  float vb = nh2B * fw;
#pragma unroll
  for (int off = 32; off > 0; off >>= 1) {
    va += __shfl_down(va, off);
    vb += __shfl_down(vb, off);
  }
  if (j == 0) {
    const float fb = fcb[0];
    out[b0]     = va + fb;
    out[b0 + 1] = vb + fb;
  }
}

extern "C" void kernel_launch(void* const* d_in, const int* in_sizes, int n_in,
                              void* d_out, int out_size, void* d_ws, size_t ws_size,
                              hipStream_t stream) {
  (void)in_sizes; (void)n_in; (void)d_ws; (void)ws_size; (void)out_size;
  const float* x    = (const float*)d_in[0];
  const float* wih0 = (const float*)d_in[1];
  const float* whh0 = (const float*)d_in[2];
  const float* bih0 = (const float*)d_in[3];
  const float* bhh0 = (const float*)d_in[4];
  const float* wih1 = (const float*)d_in[5];
  const float* whh1 = (const float*)d_in[6];
  const float* bih1 = (const float*)d_in[7];
  const float* bhh1 = (const float*)d_in[8];
  const float* wih2 = (const float*)d_in[9];
  const float* whh2 = (const float*)d_in[10];
  const float* bih2 = (const float*)d_in[11];
  const float* bhh2 = (const float*)d_in[12];
  const float* fcw  = (const float*)d_in[13];
  const float* fcb  = (const float*)d_in[14];
  float* out = (float*)d_out;

  hipLaunchKernelGGL(rnn3_fused, dim3(B_ / 2), dim3(64), 0, stream,
                     x, wih0, whh0, bih0, bhh0,
                     wih1, whh1, bih1, bhh1,
                     wih2, whh2, bih2, bhh2,
                     fcw, fcb, out);
}

// Round 15
// 897.471 us; speedup vs baseline: 2.1330x; 2.1330x over previous
//
#include <hip/hip_runtime.h>
#include <cstddef>
#include <cstdint>

#define B_ 512
#define T_ 2048
#define I_ 16
#define H_ 40

typedef __fp16 half_t;
typedef half_t h2 __attribute__((ext_vector_type(2)));
typedef float f4 __attribute__((ext_vector_type(4)));

// tanh(x) = 1 - 2/(exp(2x)+1); exp(2x) = exp2(x * 2*log2(e)).
__device__ __forceinline__ float fast_tanh(float x) {
  float e = __builtin_amdgcn_exp2f(x * 2.8853900817779268f);
  return 1.0f - 2.0f * __builtin_amdgcn_rcpf(e + 1.0f);
}
// v_dot2_f32_f16: 2 fp16 MACs with f32 accumulate (all-VGPR operands now).
__device__ __forceinline__ float dot2(h2 a, h2 b, float c) {
  return __builtin_amdgcn_fdot2(a, b, c, false);
}
// Use-site fp16 pack for x (volatile anchor after WAITX; r9-proven).
__device__ __forceinline__ h2 cvtpk_v(float lo, float hi) {
  h2 r;
  asm volatile("v_cvt_pkrtz_f16_f32 %0, %1, %2" : "=v"(r) : "v"(lo), "v"(hi));
  return r;
}
#define PIN(v) asm volatile("" : "+v"(v))

// ---- async x machinery (r11-proven, unchanged) ----
#define GLOADQ(R0, R1, R2, R3, P, O0, O1, O2, O3)                   \
  asm volatile("global_load_dwordx4 %0, %4, off offset:" #O0 "\n\t" \
               "global_load_dwordx4 %1, %4, off offset:" #O1 "\n\t" \
               "global_load_dwordx4 %2, %4, off offset:" #O2 "\n\t" \
               "global_load_dwordx4 %3, %4, off offset:" #O3        \
               : "=&v"(R0), "=&v"(R1), "=&v"(R2), "=&v"(R3)         \
               : "v"(P))
#define WAITX(N) asm volatile("s_waitcnt vmcnt(" #N ")")

// Pack one f32 weight row into resident half2 VGPRs.
#define LOADW(DST, SRC, STR, N2)                                    \
  _Pragma("unroll") for (int k = 0; k < (N2); ++k) {                \
    DST[k][0] = (half_t)SRC[jr * (STR) + 2 * k];                    \
    DST[k][1] = (half_t)SRC[jr * (STR) + 2 * k + 1];                \
    PIN(DST[k]);                                                    \
  }

// Register h broadcast via ds_bpermute (round-15 probe: replaces readlane).
//  1. dpp quad_perm [1,0,3,2]: each lane gets XOR-1 partner's h
//  2. cvt_pkrtz: even lane 2p holds pack(h[2p],h[2p+1])
//  3. 20 ds_bpermute with uniform addr 8p -> pair p broadcast into a VGPR.
// No SGPR writes in the loop; compiler inserts the lgkmcnt waits itself.
#define BCAST(NH, PAIRS) do {                                       \
  int nb_ = __builtin_amdgcn_update_dpp(                            \
      0, __builtin_bit_cast(int, (NH)), 0xB1, 0xf, 0xf, false);     \
  h2 pk_ = __builtin_amdgcn_cvt_pkrtz((NH),                         \
      __builtin_bit_cast(float, nb_));                              \
  int pkb_ = __builtin_bit_cast(int, pk_);                          \
  _Pragma("unroll") for (int p = 0; p < H_ / 2; ++p)                \
    PAIRS[p] = __builtin_bit_cast(h2,                               \
        __builtin_amdgcn_ds_bpermute(8 * p, pkb_));                 \
} while (0)

// 40-wide dot: 20 dot2 of broadcast (uniform-VGPR) pairs vs resident weights.
#define HDS(PAIRS, W, A0, A1, A2, A3)                               \
  _Pragma("unroll") for (int p = 0; p < 5; ++p) {                   \
    A0 = dot2(PAIRS[4 * p + 0], (W)[4 * p + 0], A0);                \
    A1 = dot2(PAIRS[4 * p + 1], (W)[4 * p + 1], A1);                \
    A2 = dot2(PAIRS[4 * p + 2], (W)[4 * p + 2], A2);                \
    A3 = dot2(PAIRS[4 * p + 3], (W)[4 * p + 3], A3);                \
  }

// One RNN time step, zero LDS allocation (r10/r11 structure).
#define STEP(XH) do {                                               \
  float a0 = bias0, a1 = 0.f, a2 = 0.f, a3 = 0.f;                   \
  a0 = dot2(XH[0], w0i[0], a0); a1 = dot2(XH[1], w0i[1], a1);       \
  a2 = dot2(XH[2], w0i[2], a2); a3 = dot2(XH[3], w0i[3], a3);       \
  a0 = dot2(XH[4], w0i[4], a0); a1 = dot2(XH[5], w0i[5], a1);       \
  a2 = dot2(XH[6], w0i[6], a2); a3 = dot2(XH[7], w0i[7], a3);       \
  HDS(hp0, w0h, a0, a1, a2, a3);  /* old h0 */                      \
  const float nh0 = fast_tanh((a0 + a1) + (a2 + a3));               \
  BCAST(nh0, hp0);                                                  \
  float b0 = bias1, b1 = 0.f, b2 = 0.f, b3 = 0.f;                   \
  HDS(hp0, w1i, b0, b1, b2, b3);  /* NEW h0 */                      \
  HDS(hp1, w1h, b0, b1, b2, b3);  /* old h1 */                      \
  const float nh1 = fast_tanh((b0 + b1) + (b2 + b3));               \
  BCAST(nh1, hp1);                                                  \
  float c0 = bias2, c1 = 0.f, c2 = 0.f, c3 = 0.f;                   \
  HDS(hp1, w2i, c0, c1, c2, c3);  /* NEW h1 */                      \
  HDS(hp2, w2h, c0, c1, c2, c3);  /* old h2 */                      \
  nh2v = fast_tanh((c0 + c1) + (c2 + c3));                          \
  BCAST(nh2v, hp2);                                                 \
} while (0)

#define PACKX(XH, R0, R1, R2, R3)                                   \
  do {                                                              \
    XH[0] = cvtpk_v(R0[0], R0[1]); XH[1] = cvtpk_v(R0[2], R0[3]);   \
    XH[2] = cvtpk_v(R1[0], R1[1]); XH[3] = cvtpk_v(R1[2], R1[3]);   \
    XH[4] = cvtpk_v(R2[0], R2[1]); XH[5] = cvtpk_v(R2[2], R2[3]);   \
    XH[6] = cvtpk_v(R3[0], R3[1]); XH[7] = cvtpk_v(R3[2], R3[3]);   \
  } while (0)

__global__ __launch_bounds__(64)
__attribute__((amdgpu_waves_per_eu(1, 1)))  // full 512-reg budget
void rnn3_fused(const float* __restrict__ x,
                const float* __restrict__ wih0, const float* __restrict__ whh0,
                const float* __restrict__ bih0, const float* __restrict__ bhh0,
                const float* __restrict__ wih1, const float* __restrict__ whh1,
                const float* __restrict__ b_ih1, const float* __restrict__ bhh1,
                const float* __restrict__ wih2, const float* __restrict__ whh2,
                const float* __restrict__ bih2, const float* __restrict__ bhh2,
                const float* __restrict__ fcw, const float* __restrict__ fcb,
                float* __restrict__ out) {
  const int b = blockIdx.x;
  const int j = threadIdx.x;
  const int jr = (j < H_) ? j : (H_ - 1);

  // ---- weights packed fp16: 108 resident VGPRs ----
  h2 w0i[I_ / 2], w0h[H_ / 2], w1i[H_ / 2], w1h[H_ / 2], w2i[H_ / 2], w2h[H_ / 2];
  LOADW(w0i, wih0, I_, I_ / 2)
  LOADW(w0h, whh0, H_, H_ / 2)
  LOADW(w1i, wih1, H_, H_ / 2)
  LOADW(w1h, whh1, H_, H_ / 2)
  LOADW(w2i, wih2, H_, H_ / 2)
  LOADW(w2h, whh2, H_, H_ / 2)

  float bias0 = bih0[jr] + bhh0[jr];  PIN(bias0);
  float bias1 = b_ih1[jr] + bhh1[jr]; PIN(bias1);
  float bias2 = bih2[jr] + bhh2[jr];  PIN(bias2);

  // h state as 3x20 uniform VGPR fp16 pairs (h(0)=0)
  h2 hp0[H_ / 2], hp1[H_ / 2], hp2[H_ / 2];
#pragma unroll
  for (int p = 0; p < H_ / 2; ++p) {
    hp0[p] = h2{(half_t)0.f, (half_t)0.f};
    hp1[p] = h2{(half_t)0.f, (half_t)0.f};
    hp2[p] = h2{(half_t)0.f, (half_t)0.f};
  }

  const float* __restrict__ xb = x + (size_t)b * (T_ * I_);

  // Four async 64B x buffers = one 4-step group in flight (16 loads).
  f4 rA0, rA1, rA2, rA3, rB0, rB1, rB2, rB3;
  f4 rC0, rC1, rC2, rC3, rD0, rD1, rD2, rD3;
  GLOADQ(rA0, rA1, rA2, rA3, xb,   0,  16,  32,  48);
  GLOADQ(rB0, rB1, rB2, rB3, xb,  64,  80,  96, 112);
  GLOADQ(rC0, rC1, rC2, rC3, xb, 128, 144, 160, 176);
  GLOADQ(rD0, rD1, rD2, rD3, xb, 192, 208, 224, 240);

  float nh2v = 0.f;
  h2 xh[8];

  for (int t = 0; t < T_; t += 4) {
    const float* pf = xb + (size_t)((t + 4 < T_) ? (t + 4) : (T_ - 4)) * I_;
    WAITX(12);
    PACKX(xh, rA0, rA1, rA2, rA3);
    STEP(xh);
    GLOADQ(rA0, rA1, rA2, rA3, pf,   0,  16,  32,  48);
    WAITX(12);
    PACKX(xh, rB0, rB1, rB2, rB3);
    STEP(xh);
    GLOADQ(rB0, rB1, rB2, rB3, pf,  64,  80,  96, 112);
    WAITX(12);
    PACKX(xh, rC0, rC1, rC2, rC3);
    STEP(xh);
    GLOADQ(rC0, rC1, rC2, rC3, pf, 128, 144, 160, 176);
    WAITX(12);
    PACKX(xh, rD0, rD1, rD2, rD3);
    STEP(xh);
    GLOADQ(rD0, rD1, rD2, rD3, pf, 192, 208, 224, 240);
  }

  // Drain async loads before their destination registers are reused.
  asm volatile("s_waitcnt vmcnt(0)");
  PIN(rA0); PIN(rA1); PIN(rA2); PIN(rA3);
  PIN(rB0); PIN(rB1); PIN(rB2); PIN(rB3);
  PIN(rC0); PIN(rC1); PIN(rC2); PIN(rC3);
  PIN(rD0); PIN(rD1); PIN(rD2); PIN(rD3);

  // ---- FC head: out[b] = sum_j fc_w[j]*h2[j] + fc_b ----
  const float fw = (j < H_) ? fcw[j] : 0.f;
  float v = nh2v * fw;
#pragma unroll
  for (int off = 32; off > 0; off >>= 1) v += __shfl_down(v, off);
  if (j == 0) out[b] = v + fcb[0];
}

extern "C" void kernel_launch(void* const* d_in, const int* in_sizes, int n_in,
                              void* d_out, int out_size, void* d_ws, size_t ws_size,
                              hipStream_t stream) {
  (void)in_sizes; (void)n_in; (void)d_ws; (void)ws_size; (void)out_size;
  const float* x    = (const float*)d_in[0];
  const float* wih0 = (const float*)d_in[1];
  const float* whh0 = (const float*)d_in[2];
  const float* bih0 = (const float*)d_in[3];
  const float* bhh0 = (const float*)d_in[4];
  const float* wih1 = (const float*)d_in[5];
  const float* whh1 = (const float*)d_in[6];
  const float* bih1 = (const float*)d_in[7];
  const float* bhh1 = (const float*)d_in[8];
  const float* wih2 = (const float*)d_in[9];
  const float* whh2 = (const float*)d_in[10];
  const float* bih2 = (const float*)d_in[11];
  const float* bhh2 = (const float*)d_in[12];
  const float* fcw  = (const float*)d_in[13];
  const float* fcb  = (const float*)d_in[14];
  float* out = (float*)d_out;

  hipLaunchKernelGGL(rnn3_fused, dim3(B_), dim3(64), 0, stream,
                     x, wih0, whh0, bih0, bhh0,
                     wih1, whh1, bih1, bhh1,
                     wih2, whh2, bih2, bhh2,
                     fcw, fcb, out);
}